// Round 17
// baseline (322.243 us; speedup 1.0000x reference)
//
#include <hip/hip_runtime.h>
#include <cstdint>
#include <cstddef>

// ---------- types ----------
typedef __bf16 bf16x8 __attribute__((ext_vector_type(8)));
typedef float  f32x4  __attribute__((ext_vector_type(4)));
typedef int    i32x4  __attribute__((ext_vector_type(4)));
typedef unsigned short u16x4 __attribute__((ext_vector_type(4)));

#define DEV __device__ __forceinline__
#define NEGINF (-__builtin_inff())

DEV uint16_t f2bf(float f) {
  union { float f; uint32_t u; } v; v.f = f;
  uint32_t u = v.u;
  u += 0x7FFFu + ((u >> 16) & 1u);   // RNE
  return (uint16_t)(u >> 16);
}
DEV float bf2f(uint16_t h) {
  union { uint32_t u; float f; } v; v.u = ((uint32_t)h) << 16;
  return v.f;
}

// async global->LDS, 16B per lane. LDS dest must be wave-uniform base (+lane*16).
DEV void gload_lds16(const void* g, void* l) {
  __builtin_amdgcn_global_load_lds(
      (const __attribute__((address_space(1))) void*)g,
      (__attribute__((address_space(3))) void*)l, 16, 0, 0);
}

// ---------- constants ----------
// B=2 S=2048 HID=2560 NH=20 NKV=5 HD=128 GROUPS=4

// ---------- prep kernels ----------
__global__ void k_f32_to_bf16(const float* __restrict__ in, uint16_t* __restrict__ out, int n4) {
  int i = blockIdx.x * blockDim.x + threadIdx.x;
  if (i >= n4) return;
  f32x4 v = *(const f32x4*)(in + (size_t)i * 4);
  u16x4 o;
  o[0] = f2bf(v[0]); o[1] = f2bf(v[1]); o[2] = f2bf(v[2]); o[3] = f2bf(v[3]);
  *(u16x4*)(out + (size_t)i * 4) = o;
}

// All 4 ternary unpacks in ONE launch; attn_norm gain folded into O weights.
__global__ void k_unpack_all(const uint32_t* __restrict__ qw, const uint32_t* __restrict__ kw,
                             const uint32_t* __restrict__ vw, const uint32_t* __restrict__ ow,
                             uint16_t* __restrict__ wqkv, uint16_t* __restrict__ owb,
                             const float* __restrict__ g) {
  int idx = blockIdx.x * blockDim.x + threadIdx.x;
  if (idx >= 4096000) return;
  if (idx < 2457600) {
    int local = (idx < 1638400) ? idx : ((idx < 2048000) ? idx - 1638400 : idx - 2048000);
    const uint32_t* s = (idx < 1638400) ? qw : ((idx < 2048000) ? kw : vw);
    uint32_t b = s[local] & 0xFFu;
    int drow = idx / 640, pc = idx - drow * 640;
    int blk = pc >> 5, j = pc & 31;
    size_t base = (size_t)drow * 2560 + (size_t)blk * 128 + j;
    wqkv[base]      = f2bf((float)((b >> 6) & 3u) - 1.0f);
    wqkv[base + 32] = f2bf((float)((b >> 4) & 3u) - 1.0f);
    wqkv[base + 64] = f2bf((float)((b >> 2) & 3u) - 1.0f);
    wqkv[base + 96] = f2bf((float)(b & 3u) - 1.0f);
  } else {
    int local = idx - 2457600;
    uint32_t b = ow[local] & 0xFFu;
    int drow = local / 640, pc = local - drow * 640;
    int blk = pc >> 5, j = pc & 31;
    int kpos = blk * 128 + j;
    size_t base = (size_t)drow * 2560 + kpos;
    owb[base]      = f2bf(((float)((b >> 6) & 3u) - 1.0f) * g[kpos]);
    owb[base + 32] = f2bf(((float)((b >> 4) & 3u) - 1.0f) * g[kpos + 32]);
    owb[base + 64] = f2bf(((float)((b >> 2) & 3u) - 1.0f) * g[kpos + 64]);
    owb[base + 96] = f2bf(((float)(b & 3u) - 1.0f) * g[kpos + 96]);
  }
}

__global__ void k_rope_table(float* __restrict__ cosT, float* __restrict__ sinT) {
  int idx = blockIdx.x * blockDim.x + threadIdx.x;  // 2048*64
  int s = idx >> 6, i = idx & 63;
  float inv = expf((float)i * (-13.122363377404328f / 64.0f));
  float fr = (float)s * inv;
  cosT[idx] = cosf(fr);
  sinT[idx] = sinf(fr);
}

// in-place RoPE on (rows, H heads, 128) bf16; pair (d, d+64). Used for K only.
__global__ void k_rope(uint16_t* __restrict__ buf, const float* __restrict__ cosT,
                       const float* __restrict__ sinT, int H, int total) {
  int idx = blockIdx.x * blockDim.x + threadIdx.x;
  if (idx >= total) return;
  int d = idx & 63;
  int t = idx >> 6;
  int h = t % H;
  int row = t / H;          // 0..4095
  int s = row & 2047;
  size_t base = (size_t)row * (size_t)(H * 128) + (size_t)h * 128 + d;
  float x1 = bf2f(buf[base]), x2 = bf2f(buf[base + 64]);
  float c = cosT[(s << 6) + d], sn = sinT[(s << 6) + d];
  buf[base]      = f2bf(x1 * c - x2 * sn);
  buf[base + 64] = f2bf(x2 * c + x1 * sn);
}

// ---------- GEMM: C[M,N] = A[M,K] * W[N,K]^T ----------
// global_load_lds(16B) staging, linear LDS + XOR-swizzle (row&7)<<4 on the
// GLOBAL source (rule 21) and on ds_read_b128 fragment reads.
// MODE 0: QKV epilogue split; MODE 1: f32 out * os * rs[row] (fused rmsnorm).
template<int MODE>
__global__ __launch_bounds__(256, 2)
void k_gemm(const uint16_t* __restrict__ A, const uint16_t* __restrict__ W,
            uint16_t* __restrict__ Qo, uint16_t* __restrict__ Ko, uint16_t* __restrict__ Vo,
            float* __restrict__ Fo,
            const float* __restrict__ s0p, const float* __restrict__ s1p, const float* __restrict__ s2p,
            int M, int N, int K)
{
  __shared__ uint16_t As[128 * 64];   // 16 KB
  __shared__ uint16_t Bs[128 * 64];   // 16 KB
  const int tid = threadIdx.x;
  const int n0 = blockIdx.x * 128, m0 = blockIdx.y * 128;
  const int lane = tid & 63, w = tid >> 6;
  const int wm = (w >> 1) * 64, wn = (w & 1) * 64;
  const int lr = lane & 15, lg = lane >> 4, lk = lg * 8;
  const size_t K2 = (size_t)K * 2;
  f32x4 acc[4][4] = {};

  const int srow = tid >> 3;                       // 0..31 (+i*32)
  const int cprime = ((tid & 7) * 16) ^ ((srow & 7) << 4);
  const uint8_t* Ag = (const uint8_t*)A + (size_t)(m0 + srow) * K2 + cprime;
  const uint8_t* Wg = (const uint8_t*)W + (size_t)(n0 + srow) * K2 + cprime;
  char* Al = (char*)As + w * 1024;                 // wave-uniform dest (+i*4096)
  char* Bl = (char*)Bs + w * 1024;

  for (size_t k0b = 0; k0b < K2; k0b += 128) {
    #pragma unroll
    for (int i = 0; i < 4; ++i)
      gload_lds16(Ag + (size_t)(i * 32) * K2 + k0b, Al + i * 4096);
    #pragma unroll
    for (int i = 0; i < 4; ++i)
      gload_lds16(Wg + (size_t)(i * 32) * K2 + k0b, Bl + i * 4096);
    __syncthreads();
    #pragma unroll
    for (int kc = 0; kc < 64; kc += 32) {
      bf16x8 a[4], b[4];
      #pragma unroll
      for (int i = 0; i < 4; ++i) {
        const int r = wm + i * 16 + lr;
        a[i] = *(const bf16x8*)((const char*)As + r * 128 + (((kc + lk) * 2) ^ ((r & 7) << 4)));
      }
      #pragma unroll
      for (int j = 0; j < 4; ++j) {
        const int r = wn + j * 16 + lr;
        b[j] = *(const bf16x8*)((const char*)Bs + r * 128 + (((kc + lk) * 2) ^ ((r & 7) << 4)));
      }
      #pragma unroll
      for (int i = 0; i < 4; ++i)
        #pragma unroll
        for (int j = 0; j < 4; ++j)
          acc[i][j] = __builtin_amdgcn_mfma_f32_16x16x32_bf16(a[i], b[j], acc[i][j], 0, 0, 0);
    }
    __syncthreads();
  }

  if (MODE == 0) {
    const float qs = *s0p, ks = *s1p, vs = *s2p;
    #pragma unroll
    for (int i = 0; i < 4; ++i) {
      const int rowb = m0 + wm + i * 16 + lg * 4;
      #pragma unroll
      for (int j = 0; j < 4; ++j) {
        const int col = n0 + wn + j * 16 + lr;
        #pragma unroll
        for (int r = 0; r < 4; ++r) {
          const int rr = rowb + r;
          const float v = acc[i][j][r];
          if (col < 2560) {
            Qo[(size_t)rr * 2560 + col] = f2bf(v * qs);
          } else if (col < 3200) {
            Ko[(size_t)rr * 640 + (col - 2560)] = f2bf(v * ks);
          } else {
            const int n2 = col - 3200;
            const int kvh = n2 >> 7, d = n2 & 127;
            const int bb = rr >> 11, ss = rr & 2047;
            Vo[(((size_t)(bb * 5 + kvh) * 128 + d) << 11) + ss] = f2bf(v * vs);
          }
        }
      }
    }
  } else {
    const float os = *s0p;          // s1p = rs[] per-row rmsnorm scale
    #pragma unroll
    for (int i = 0; i < 4; ++i) {
      const int rowb = m0 + wm + i * 16 + lg * 4;
      #pragma unroll
      for (int j = 0; j < 4; ++j) {
        const int col = n0 + wn + j * 16 + lr;
        #pragma unroll
        for (int r = 0; r < 4; ++r)
          Fo[(size_t)(rowb + r) * N + col] = acc[i][j][r] * os * s1p[rowb + r];
      }
    }
  }
}

// ---------- flash attention (KVBLK=32, 40960B LDS -> 4 blocks/CU, merged-V PV) ----------
// R12's kernel (functionally verified, absmax 0.031) with the launch-bound fix:
// (256,2) not (256,4) — R12's VGPR-64 cap caused spills (WRITE_SIZE 78MB), not the
// structure. Expect VGPR ~90-105 -> 4 blocks/CU (LDS-capped: 4*40960=163840 exact).
// Swizzles (both sides, rule 21): K (row&7)<<4; V 64B-rows (row&3)<<4;
// P tile (lr&3)<<3 element-XOR.
__global__ __launch_bounds__(256, 2)
void k_attn(const uint16_t* __restrict__ Q, const uint16_t* __restrict__ Kb,
            const uint16_t* __restrict__ Vt, uint16_t* __restrict__ Ob,
            const float* __restrict__ cosT, const float* __restrict__ sinT)
{
  __shared__ char Klds[2][8192];          // [32 k][128 d] bf16, swizzled
  __shared__ char Vlds[2][8192];          // [128 d][32 k] bf16, swizzled
  __shared__ uint16_t p_lds[4][2][16][32];  // per-wave, per-group P tile
  // total LDS = 16384+16384+8192 = 40960 B -> exactly 4 blocks/CU

  // XCD-chunked remap (blockIdx%8 = XCD): 80 consecutive strips per XCD.
  const int lin = blockIdx.x;                            // 0..639
  const int gslot = (lin & 7) * 80 + (lin >> 3);
  const int bk = gslot >> 6;                             // 0..9
  const int st = 63 - (gslot & 63);                      // strip32 id, heavy-first
  const int b = bk / 5, kvh = bk - b * 5;

  const int tid = threadIdx.x, lane = tid & 63, w = tid >> 6;
  const int lr = lane & 15, lg = lane >> 4, lk = lg * 8;
  const int h = kvh * 4 + w;                             // this wave's q-head
  uint16_t (*pl)[16][32] = p_lds[w];
  const int kswz = (lr & 7) << 4;
  const int vswz = (lr & 3) << 4;
  const int pswz = (lr & 3) << 3;

  const uint8_t* Kg = (const uint8_t*)(Kb + (size_t)b * 2048 * 640 + (size_t)kvh * 128);
  const uint8_t* Vg = (const uint8_t*)(Vt + ((size_t)(b * 5 + kvh) * 128) * 2048);

  // staging coords (256 threads cover each 8KB tile in 2 x 16B rounds)
  const int krow = tid >> 4;                             // K: row 0..15 (+16i); 256B rows
  const int kcol = ((tid & 15) * 16) ^ ((krow & 7) << 4);
  const int vrow = tid >> 2;                             // V: row 0..63 (+64i); 64B rows
  const int vcol = ((tid & 3) * 16) ^ ((vrow & 3) << 4);
  const int dst16 = tid * 16;

  const float C = 0.127531019577f;        // (1/sqrt(128)) * log2(e)

  const int q0 = st * 32;                 // rows q0..q0+31; group g rows q0+16g+lr
  const int ns = st + 1;                  // 32-wide k-steps (kend = q0+32)

  bf16x8 qf0[4], qf1[4];
  {
    const size_t qb0 = ((size_t)(b * 2048 + q0 + lr)) * 2560 + (size_t)h * 128 + lk;
    #pragma unroll
    for (int c = 0; c < 4; ++c) {
      qf0[c] = *(const bf16x8*)&Q[qb0 + c * 32];
      qf1[c] = *(const bf16x8*)&Q[qb0 + 16 * 2560 + c * 32];
    }
  }
  // in-register RoPE on Q (pairs: qf[c][j] <-> qf[c+2][j], d = 32c+8lg+j)
  #pragma unroll
  for (int g = 0; g < 2; ++g) {
    bf16x8* qf = g ? qf1 : qf0;
    const int s = q0 + 16 * g + lr;
    const int tb0 = s * 64 + lg * 8;
    #pragma unroll
    for (int c = 0; c < 2; ++c) {
      const int tb = tb0 + c * 32;
      f32x4 csa = *(const f32x4*)&cosT[tb];
      f32x4 csb = *(const f32x4*)&cosT[tb + 4];
      f32x4 sna = *(const f32x4*)&sinT[tb];
      f32x4 snb = *(const f32x4*)&sinT[tb + 4];
      #pragma unroll
      for (int j = 0; j < 8; ++j) {
        const float cs = (j < 4) ? csa[j] : csb[j - 4];
        const float sn = (j < 4) ? sna[j] : snb[j - 4];
        const float x1 = (float)qf[c][j], x2 = (float)qf[c + 2][j];
        qf[c][j]     = (__bf16)(x1 * cs - x2 * sn);
        qf[c + 2][j] = (__bf16)(x2 * cs + x1 * sn);
      }
    }
  }

  // prologue: stage step-0 K/V into buf 0
  {
    const uint8_t* Ks = Kg + (size_t)krow * 1280 + kcol;
    const uint8_t* Vs = Vg + (size_t)vrow * 4096 + vcol;
    #pragma unroll
    for (int i = 0; i < 2; ++i) gload_lds16(Ks + (size_t)i * 16 * 1280, Klds[0] + dst16 + i * 4096);
    #pragma unroll
    for (int i = 0; i < 2; ++i) gload_lds16(Vs + (size_t)i * 64 * 4096, Vlds[0] + dst16 + i * 4096);
  }

  int cur = 0;
  float m0 = NEGINF, m1 = NEGINF, l0 = 0.f, l1 = 0.f;
  f32x4 oa0[8] = {}, oa1[8] = {};

  #pragma unroll 1
  for (int stp = 0; stp < ns; ++stp) {
    const int k0 = stp * 32;
    __syncthreads();   // implicit vmcnt(0): tile[cur] landed (flew over previous step)

    if (stp + 1 < ns) {
      const int kn = k0 + 32;
      const uint8_t* Ks = Kg + (size_t)(kn + krow) * 1280 + kcol;
      const uint8_t* Vs = Vg + (size_t)vrow * 4096 + (size_t)kn * 2 + vcol;
      char* Kd = Klds[cur ^ 1] + dst16;
      char* Vd = Vlds[cur ^ 1] + dst16;
      #pragma unroll
      for (int i = 0; i < 2; ++i) gload_lds16(Ks + (size_t)i * 16 * 1280, Kd + i * 4096);
      #pragma unroll
      for (int i = 0; i < 2; ++i) gload_lds16(Vs + (size_t)i * 64 * 4096, Vd + i * 4096);
    }

    const char* Kc = Klds[cur];
    const char* Vc = Vlds[cur];

    // QK^T both groups; each kf fragment feeds 2 MFMAs
    __builtin_amdgcn_s_setprio(1);
    f32x4 sa0[2] = {}, sa1[2] = {};
    #pragma unroll
    for (int t = 0; t < 2; ++t) {
      #pragma unroll
      for (int c = 0; c < 4; ++c) {
        bf16x8 kf = *(const bf16x8*)(Kc + (t * 16 + lr) * 256 + ((c * 64 + lg * 16) ^ kswz));
        sa0[t] = __builtin_amdgcn_mfma_f32_16x16x32_bf16(kf, qf0[c], sa0[t], 0, 0, 0);
        sa1[t] = __builtin_amdgcn_mfma_f32_16x16x32_bf16(kf, qf1[c], sa1[t], 0, 0, 0);
      }
    }
    __builtin_amdgcn_s_setprio(0);

    // per-group softmax -> P tiles; then ONE merged PV pass
    #pragma unroll
    for (int g = 0; g < 2; ++g) {
      const f32x4* sa = g ? sa1 : sa0;
      f32x4* oa = g ? oa1 : oa0;
      float& m = g ? m1 : m0;
      float& l = g ? l1 : l0;
      const int q0g = q0 + 16 * g;

      float sraw[8];
      if (k0 + 31 > q0g) {
        #pragma unroll
        for (int t = 0; t < 2; ++t)
          #pragma unroll
          for (int r = 0; r < 4; ++r)
            sraw[t * 4 + r] = (k0 + t * 16 + lg * 4 + r <= q0g + lr) ? sa[t][r] : NEGINF;
      } else {
        #pragma unroll
        for (int t = 0; t < 2; ++t)
          #pragma unroll
          for (int r = 0; r < 4; ++r)
            sraw[t * 4 + r] = sa[t][r];
      }
      // raw max tree (7) + 2 shuffles, scale once
      float a01 = fmaxf(sraw[0], sraw[1]), a23 = fmaxf(sraw[2], sraw[3]);
      float a45 = fmaxf(sraw[4], sraw[5]), a67 = fmaxf(sraw[6], sraw[7]);
      float mxr = fmaxf(fmaxf(a01, a23), fmaxf(a45, a67));
      mxr = fmaxf(mxr, __shfl_xor(mxr, 16));
      mxr = fmaxf(mxr, __shfl_xor(mxr, 32));
      const float mx_u = mxr * C;
      // defer-max: skip rescale while max growth bounded (values <= 2^8)
      if (!__all(mx_u <= m + 8.0f)) {
        const float mn = fmaxf(m, mx_u);
        const float resc = __builtin_exp2f(m - mn);
        m = mn;
        l *= resc;
        #pragma unroll
        for (int dc = 0; dc < 8; ++dc) {
          oa[dc][0] *= resc; oa[dc][1] *= resc; oa[dc][2] *= resc; oa[dc][3] *= resc;
        }
      }
      const float nm = -m;
      float pv[8];
      #pragma unroll
      for (int i = 0; i < 8; ++i) pv[i] = __builtin_exp2f(fmaf(sraw[i], C, nm));
      l += ((pv[0] + pv[1]) + (pv[2] + pv[3])) + ((pv[4] + pv[5]) + (pv[6] + pv[7]));
      // P -> LDS: row q=lr, k = 16t + lg*4 + r, cols XOR'd by pswz
      #pragma unroll
      for (int t = 0; t < 2; ++t) {
        union { __bf16 b4[4]; unsigned long long u64; } pk;
        #pragma unroll
        for (int r = 0; r < 4; ++r) pk.b4[r] = (__bf16)pv[t * 4 + r];
        *(unsigned long long*)&pl[g][lr][(t * 16 + lg * 4) ^ pswz] = pk.u64;
      }
    }

    // merged PV: one vf read feeds both groups
    bf16x8 paA = *(const bf16x8*)&pl[0][lr][lk ^ pswz];
    bf16x8 paB = *(const bf16x8*)&pl[1][lr][lk ^ pswz];
    __builtin_amdgcn_s_setprio(1);
    #pragma unroll
    for (int dc = 0; dc < 8; ++dc) {
      bf16x8 vf = *(const bf16x8*)(Vc + (dc * 16 + lr) * 64 + ((lg * 16) ^ vswz));
      oa0[dc] = __builtin_amdgcn_mfma_f32_16x16x32_bf16(vf, paA, oa0[dc], 0, 0, 0);
      oa1[dc] = __builtin_amdgcn_mfma_f32_16x16x32_bf16(vf, paB, oa1[dc], 0, 0, 0);
    }
    __builtin_amdgcn_s_setprio(0);
    cur ^= 1;
  }

  // finalize both groups
  #pragma unroll
  for (int g = 0; g < 2; ++g) {
    f32x4* oa = g ? oa1 : oa0;
    float lf = g ? l1 : l0;
    lf += __shfl_xor(lf, 16);
    lf += __shfl_xor(lf, 32);
    const float inv = 1.0f / lf;
    const size_t obase = ((size_t)(b * 2048 + q0 + 16 * g + lr)) * 2560 + (size_t)h * 128;
    #pragma unroll
    for (int dc = 0; dc < 8; ++dc) {
      union { __bf16 b4[4]; unsigned long long u64; } ok;
      #pragma unroll
      for (int r = 0; r < 4; ++r) ok.b4[r] = (__bf16)(oa[dc][r] * inv);
      *(unsigned long long*)&Ob[obase + dc * 16 + lg * 4] = ok.u64;
    }
  }
}

// ---------- row rms scale: rs[row] = rsqrt(mean(x^2)+eps) ----------
__global__ __launch_bounds__(256)
void k_rowrms(const uint16_t* __restrict__ X, float* __restrict__ rs)
{
  const int row = blockIdx.x;
  const int tid = threadIdx.x;
  const uint16_t* x = X + (size_t)row * 2560;
  float ss = 0.f;
  #pragma unroll
  for (int it = 0; it < 10; ++it) {
    const int i = tid + it * 256;
    const float v = bf2f(x[i]);
    ss += v * v;
  }
  #pragma unroll
  for (int off = 1; off < 64; off <<= 1) ss += __shfl_xor(ss, off, 64);
  __shared__ float sred[4];
  if ((tid & 63) == 0) sred[tid >> 6] = ss;
  __syncthreads();
  if (tid == 0) {
    const float tot = sred[0] + sred[1] + sred[2] + sred[3];
    rs[row] = rsqrtf(tot * (1.0f / 2560.0f) + 1e-6f);
  }
}

// ---------- launch ----------
extern "C" void kernel_launch(void* const* d_in, const int* in_sizes, int n_in,
                              void* d_out, int out_size, void* d_ws, size_t ws_size,
                              hipStream_t stream)
{
  const float*    x     = (const float*)d_in[0];
  // d_in[1] = attention_mask (pure causal -> analytic)
  const uint32_t* qw    = (const uint32_t*)d_in[2];  // harness promotes uint8 -> int32
  const uint32_t* kw    = (const uint32_t*)d_in[3];
  const uint32_t* vw    = (const uint32_t*)d_in[4];
  const uint32_t* ow    = (const uint32_t*)d_in[5];
  const float*    qs    = (const float*)d_in[6];
  const float*    ks    = (const float*)d_in[7];
  const float*    vs    = (const float*)d_in[8];
  const float*    os    = (const float*)d_in[9];
  const float*    gnorm = (const float*)d_in[10];

  char* ws = (char*)d_ws;
  uint16_t* xb   = (uint16_t*)(ws + 0);         // 4096x2560 bf16 (x; reused as attn-out)
  uint16_t* wqkv = (uint16_t*)(ws + 20971520);  // 3840x2560 bf16
  uint16_t* owb  = (uint16_t*)(ws + 40632320);  // 2560x2560 bf16 (g-folded)
  float*    cosT = (float*)   (ws + 53739520);  // 2048x64 f32
  float*    sinT = (float*)   (ws + 54263808);  // 2048x64 f32
  uint16_t* Qb   = (uint16_t*)(ws + 54788096);  // 4096x2560 bf16 (un-roped Q)
  uint16_t* Kb   = (uint16_t*)(ws + 75759616);  // 4096x640 bf16
  uint16_t* Vt   = (uint16_t*)(ws + 81002496);  // 10x128x2048 bf16
  float*    rsb  = (float*)   (ws + 54788096);  // rs[4096] f32 (reuses dead Qb after attn)

  k_f32_to_bf16<<<10240, 256, 0, stream>>>(x, xb, 2621440);
  k_unpack_all<<<16000, 256, 0, stream>>>(qw, kw, vw, ow, wqkv, owb, gnorm);
  k_rope_table<<<512, 256, 0, stream>>>(cosT, sinT);

  k_gemm<0><<<dim3(30, 32), 256, 0, stream>>>(xb, wqkv, Qb, Kb, Vt, nullptr,
                                              qs, ks, vs, 4096, 3840, 2560);
  k_rope<<<5120, 256, 0, stream>>>(Kb, cosT, sinT, 5, 1310720);

  k_attn<<<dim3(640), 256, 0, stream>>>(Qb, Kb, Vt, xb, cosT, sinT);

  k_rowrms<<<4096, 256, 0, stream>>>(xb, rsb);

  k_gemm<1><<<dim3(20, 32), 256, 0, stream>>>(xb, owb, nullptr, nullptr, nullptr,
                                              (float*)d_out, os, rsb, nullptr,
                                              4096, 2560, 2560);
}

// Round 18
// 287.789 us; speedup vs baseline: 1.1197x; 1.1197x over previous
//
#include <hip/hip_runtime.h>
#include <cstdint>
#include <cstddef>

// ---------- types ----------
typedef __bf16 bf16x8 __attribute__((ext_vector_type(8)));
typedef float  f32x4  __attribute__((ext_vector_type(4)));
typedef int    i32x4  __attribute__((ext_vector_type(4)));
typedef unsigned short u16x4 __attribute__((ext_vector_type(4)));

#define DEV __device__ __forceinline__
#define NEGINF (-__builtin_inff())

DEV uint16_t f2bf(float f) {
  union { float f; uint32_t u; } v; v.f = f;
  uint32_t u = v.u;
  u += 0x7FFFu + ((u >> 16) & 1u);   // RNE
  return (uint16_t)(u >> 16);
}
DEV float bf2f(uint16_t h) {
  union { uint32_t u; float f; } v; v.u = ((uint32_t)h) << 16;
  return v.f;
}

// async global->LDS, 16B per lane. LDS dest must be wave-uniform base (+lane*16).
DEV void gload_lds16(const void* g, void* l) {
  __builtin_amdgcn_global_load_lds(
      (const __attribute__((address_space(1))) void*)g,
      (__attribute__((address_space(3))) void*)l, 16, 0, 0);
}

// ---------- constants ----------
// B=2 S=2048 HID=2560 NH=20 NKV=5 HD=128 GROUPS=4

// ---------- fused prep: f32->bf16 | ternary unpack (g-folded O) | rope table ----------
// blocks [0,10240): x f32 -> bf16 (4 elems/thread)
// blocks [10240,26240): unpack q/k/v -> wqkv, o -> owb (attn_norm gain folded)
// blocks [26240,26752): rope cos/sin table (2048x64)
__global__ void k_prep(const float* __restrict__ x, uint16_t* __restrict__ xb,
                       const uint32_t* __restrict__ qw, const uint32_t* __restrict__ kw,
                       const uint32_t* __restrict__ vw, const uint32_t* __restrict__ ow,
                       uint16_t* __restrict__ wqkv, uint16_t* __restrict__ owb,
                       const float* __restrict__ g,
                       float* __restrict__ cosT, float* __restrict__ sinT)
{
  const int bid = blockIdx.x, tid = threadIdx.x;
  if (bid < 10240) {
    const int i = bid * 256 + tid;             // < 2621440
    f32x4 v = *(const f32x4*)(x + (size_t)i * 4);
    u16x4 o;
    o[0] = f2bf(v[0]); o[1] = f2bf(v[1]); o[2] = f2bf(v[2]); o[3] = f2bf(v[3]);
    *(u16x4*)(xb + (size_t)i * 4) = o;
  } else if (bid < 26240) {
    const int idx = (bid - 10240) * 256 + tid; // < 4096000
    if (idx < 2457600) {
      int local = (idx < 1638400) ? idx : ((idx < 2048000) ? idx - 1638400 : idx - 2048000);
      const uint32_t* s = (idx < 1638400) ? qw : ((idx < 2048000) ? kw : vw);
      uint32_t b = s[local] & 0xFFu;
      int drow = idx / 640, pc = idx - drow * 640;
      int blk = pc >> 5, j = pc & 31;
      size_t base = (size_t)drow * 2560 + (size_t)blk * 128 + j;
      wqkv[base]      = f2bf((float)((b >> 6) & 3u) - 1.0f);
      wqkv[base + 32] = f2bf((float)((b >> 4) & 3u) - 1.0f);
      wqkv[base + 64] = f2bf((float)((b >> 2) & 3u) - 1.0f);
      wqkv[base + 96] = f2bf((float)(b & 3u) - 1.0f);
    } else {
      int local = idx - 2457600;
      uint32_t b = ow[local] & 0xFFu;
      int drow = local / 640, pc = local - drow * 640;
      int blk = pc >> 5, j = pc & 31;
      int kpos = blk * 128 + j;
      size_t base = (size_t)drow * 2560 + kpos;
      owb[base]      = f2bf(((float)((b >> 6) & 3u) - 1.0f) * g[kpos]);
      owb[base + 32] = f2bf(((float)((b >> 4) & 3u) - 1.0f) * g[kpos + 32]);
      owb[base + 64] = f2bf(((float)((b >> 2) & 3u) - 1.0f) * g[kpos + 64]);
      owb[base + 96] = f2bf(((float)(b & 3u) - 1.0f) * g[kpos + 96]);
    }
  } else {
    const int idx = (bid - 26240) * 256 + tid; // < 131072
    const int s = idx >> 6, i = idx & 63;
    float inv = expf((float)i * (-13.122363377404328f / 64.0f));
    float fr = (float)s * inv;
    cosT[idx] = cosf(fr);
    sinT[idx] = sinf(fr);
  }
}

// in-place RoPE on K (rows, 5 heads, 128) bf16; pair (d, d+64).
// Also zeroes the 4096-float row-sumsq accumulator (runs before k_attn).
__global__ void k_rope(uint16_t* __restrict__ buf, const float* __restrict__ cosT,
                       const float* __restrict__ sinT, int H, int total,
                       float* __restrict__ ss)
{
  int idx = blockIdx.x * blockDim.x + threadIdx.x;
  if (blockIdx.x < 16) ss[blockIdx.x * 256 + threadIdx.x] = 0.f;
  if (idx >= total) return;
  int d = idx & 63;
  int t = idx >> 6;
  int h = t % H;
  int row = t / H;          // 0..4095
  int s = row & 2047;
  size_t base = (size_t)row * (size_t)(H * 128) + (size_t)h * 128 + d;
  float x1 = bf2f(buf[base]), x2 = bf2f(buf[base + 64]);
  float c = cosT[(s << 6) + d], sn = sinT[(s << 6) + d];
  buf[base]      = f2bf(x1 * c - x2 * sn);
  buf[base + 64] = f2bf(x2 * c + x1 * sn);
}

// ---------- GEMM: C[M,N] = A[M,K] * W[N,K]^T ----------
// global_load_lds(16B) staging, linear LDS + XOR-swizzle (row&7)<<4 on the
// GLOBAL source (rule 21) and on ds_read_b128 fragment reads.
// MODE 0: QKV epilogue split; MODE 1: f32 out * os * rsqrt(ss[row]/2560+eps).
template<int MODE>
__global__ __launch_bounds__(256, 2)
void k_gemm(const uint16_t* __restrict__ A, const uint16_t* __restrict__ W,
            uint16_t* __restrict__ Qo, uint16_t* __restrict__ Ko, uint16_t* __restrict__ Vo,
            float* __restrict__ Fo,
            const float* __restrict__ s0p, const float* __restrict__ s1p, const float* __restrict__ s2p,
            int M, int N, int K)
{
  __shared__ uint16_t As[128 * 64];   // 16 KB
  __shared__ uint16_t Bs[128 * 64];   // 16 KB
  const int tid = threadIdx.x;
  const int n0 = blockIdx.x * 128, m0 = blockIdx.y * 128;
  const int lane = tid & 63, w = tid >> 6;
  const int wm = (w >> 1) * 64, wn = (w & 1) * 64;
  const int lr = lane & 15, lg = lane >> 4, lk = lg * 8;
  const size_t K2 = (size_t)K * 2;
  f32x4 acc[4][4] = {};

  const int srow = tid >> 3;                       // 0..31 (+i*32)
  const int cprime = ((tid & 7) * 16) ^ ((srow & 7) << 4);
  const uint8_t* Ag = (const uint8_t*)A + (size_t)(m0 + srow) * K2 + cprime;
  const uint8_t* Wg = (const uint8_t*)W + (size_t)(n0 + srow) * K2 + cprime;
  char* Al = (char*)As + w * 1024;                 // wave-uniform dest (+i*4096)
  char* Bl = (char*)Bs + w * 1024;

  for (size_t k0b = 0; k0b < K2; k0b += 128) {
    #pragma unroll
    for (int i = 0; i < 4; ++i)
      gload_lds16(Ag + (size_t)(i * 32) * K2 + k0b, Al + i * 4096);
    #pragma unroll
    for (int i = 0; i < 4; ++i)
      gload_lds16(Wg + (size_t)(i * 32) * K2 + k0b, Bl + i * 4096);
    __syncthreads();
    #pragma unroll
    for (int kc = 0; kc < 64; kc += 32) {
      bf16x8 a[4], b[4];
      #pragma unroll
      for (int i = 0; i < 4; ++i) {
        const int r = wm + i * 16 + lr;
        a[i] = *(const bf16x8*)((const char*)As + r * 128 + (((kc + lk) * 2) ^ ((r & 7) << 4)));
      }
      #pragma unroll
      for (int j = 0; j < 4; ++j) {
        const int r = wn + j * 16 + lr;
        b[j] = *(const bf16x8*)((const char*)Bs + r * 128 + (((kc + lk) * 2) ^ ((r & 7) << 4)));
      }
      #pragma unroll
      for (int i = 0; i < 4; ++i)
        #pragma unroll
        for (int j = 0; j < 4; ++j)
          acc[i][j] = __builtin_amdgcn_mfma_f32_16x16x32_bf16(a[i], b[j], acc[i][j], 0, 0, 0);
    }
    __syncthreads();
  }

  if (MODE == 0) {
    const float qs = *s0p, ks = *s1p, vs = *s2p;
    #pragma unroll
    for (int i = 0; i < 4; ++i) {
      const int rowb = m0 + wm + i * 16 + lg * 4;
      #pragma unroll
      for (int j = 0; j < 4; ++j) {
        const int col = n0 + wn + j * 16 + lr;
        #pragma unroll
        for (int r = 0; r < 4; ++r) {
          const int rr = rowb + r;
          const float v = acc[i][j][r];
          if (col < 2560) {
            Qo[(size_t)rr * 2560 + col] = f2bf(v * qs);
          } else if (col < 3200) {
            Ko[(size_t)rr * 640 + (col - 2560)] = f2bf(v * ks);
          } else {
            const int n2 = col - 3200;
            const int kvh = n2 >> 7, d = n2 & 127;
            const int bb = rr >> 11, ss2 = rr & 2047;
            Vo[(((size_t)(bb * 5 + kvh) * 128 + d) << 11) + ss2] = f2bf(v * vs);
          }
        }
      }
    }
  } else {
    const float os = *s0p;          // s1p = ss[] per-row sum of squares
    #pragma unroll
    for (int i = 0; i < 4; ++i) {
      const int rowb = m0 + wm + i * 16 + lg * 4;
      #pragma unroll
      for (int j = 0; j < 4; ++j) {
        const int col = n0 + wn + j * 16 + lr;
        #pragma unroll
        for (int r = 0; r < 4; ++r) {
          const float rs = rsqrtf(s1p[rowb + r] * (1.0f / 2560.0f) + 1e-6f);
          Fo[(size_t)(rowb + r) * N + col] = acc[i][j][r] * os * rs;
        }
      }
    }
  }
}

// ---------- flash attention (GQA-shared K+V LDS, 32 q-rows/wave, fused Q-rope) ----------
// KVBLK=64 anchor structure (R13/R16, 121us). Added: per-row sum-of-squares of the
// stored bf16 output accumulated via atomicAdd into ss[4096] (zeroed by k_rope),
// replacing the separate k_rowrms pass. GEMM<1> computes rsqrt inline.
__global__ __launch_bounds__(256, 2)
void k_attn(const uint16_t* __restrict__ Q, const uint16_t* __restrict__ Kb,
            const uint16_t* __restrict__ Vt, uint16_t* __restrict__ Ob,
            const float* __restrict__ cosT, const float* __restrict__ sinT,
            float* __restrict__ ssb)
{
  __shared__ char Klds[2][16384];         // [64 k][128 d] bf16, swizzled
  __shared__ char Vlds[2][16384];         // [128 d][64 k] bf16, swizzled
  __shared__ uint16_t p_lds[4][16][72];   // per-wave P tile (groups sequential)

  // XCD-chunked remap (blockIdx%8 = XCD): 80 consecutive strips per XCD.
  const int lin = blockIdx.x;                            // 0..639
  const int gslot = (lin & 7) * 80 + (lin >> 3);
  const int bk = gslot >> 6;                             // 0..9
  const int st = 63 - (gslot & 63);                      // strip32 id, heavy-first
  const int b = bk / 5, kvh = bk - b * 5;

  const int tid = threadIdx.x, lane = tid & 63, w = tid >> 6;
  const int lr = lane & 15, lg = lane >> 4, lk = lg * 8;
  const int h = kvh * 4 + w;                             // this wave's q-head
  uint16_t (*pl)[72] = p_lds[w];
  const int kswz = (lr & 7) << 4;

  const uint8_t* Kg = (const uint8_t*)(Kb + (size_t)b * 2048 * 640 + (size_t)kvh * 128);
  const uint8_t* Vg = (const uint8_t*)(Vt + ((size_t)(b * 5 + kvh) * 128) * 2048);

  // staging coords (256 threads cover each 16KB tile in 4 x 16B rounds)
  const int krow = tid >> 4;                             // K: row 0..15 (+16i)
  const int kcol = ((tid & 15) * 16) ^ ((krow & 7) << 4);
  const int vrow = tid >> 3;                             // V: row 0..31 (+32i)
  const int vcol = ((tid & 7) * 16) ^ ((vrow & 7) << 4);
  const int dst16 = tid * 16;

  const float C = 0.127531019577f;        // (1/sqrt(128)) * log2(e)

  const int q0 = st * 32;                 // rows q0..q0+31; group g rows q0+16g+lr
  const int ns = (q0 + 95) >> 6;          // 64-wide k-steps

  bf16x8 qf0[4], qf1[4];
  {
    const size_t qb0 = ((size_t)(b * 2048 + q0 + lr)) * 2560 + (size_t)h * 128 + lk;
    #pragma unroll
    for (int c = 0; c < 4; ++c) {
      qf0[c] = *(const bf16x8*)&Q[qb0 + c * 32];
      qf1[c] = *(const bf16x8*)&Q[qb0 + 16 * 2560 + c * 32];
    }
  }
  // in-register RoPE on Q (pairs: qf[c][j] <-> qf[c+2][j], d = 32c+8lg+j)
  #pragma unroll
  for (int g = 0; g < 2; ++g) {
    bf16x8* qf = g ? qf1 : qf0;
    const int s = q0 + 16 * g + lr;
    const int tb0 = s * 64 + lg * 8;
    #pragma unroll
    for (int c = 0; c < 2; ++c) {
      const int tb = tb0 + c * 32;
      f32x4 csa = *(const f32x4*)&cosT[tb];
      f32x4 csb = *(const f32x4*)&cosT[tb + 4];
      f32x4 sna = *(const f32x4*)&sinT[tb];
      f32x4 snb = *(const f32x4*)&sinT[tb + 4];
      #pragma unroll
      for (int j = 0; j < 8; ++j) {
        const float cs = (j < 4) ? csa[j] : csb[j - 4];
        const float sn = (j < 4) ? sna[j] : snb[j - 4];
        const float x1 = (float)qf[c][j], x2 = (float)qf[c + 2][j];
        qf[c][j]     = (__bf16)(x1 * cs - x2 * sn);
        qf[c + 2][j] = (__bf16)(x2 * cs + x1 * sn);
      }
    }
  }

  // prologue: stage step-0 K/V into buf 0
  {
    const uint8_t* Ks = Kg + (size_t)krow * 1280 + kcol;
    const uint8_t* Vs = Vg + (size_t)vrow * 4096 + vcol;
    #pragma unroll
    for (int i = 0; i < 4; ++i) gload_lds16(Ks + (size_t)i * 16 * 1280, Klds[0] + dst16 + i * 4096);
    #pragma unroll
    for (int i = 0; i < 4; ++i) gload_lds16(Vs + (size_t)i * 32 * 4096, Vlds[0] + dst16 + i * 4096);
  }

  int cur = 0;
  float m0 = NEGINF, m1 = NEGINF, l0 = 0.f, l1 = 0.f;
  f32x4 oa0[8] = {}, oa1[8] = {};

  #pragma unroll 1
  for (int stp = 0; stp < ns; ++stp) {
    const int k0 = stp * 64;
    __syncthreads();   // implicit vmcnt(0): tile[cur] landed (flew over previous step)

    if (stp + 1 < ns) {
      const int kn = k0 + 64;
      const uint8_t* Ks = Kg + (size_t)(kn + krow) * 1280 + kcol;
      const uint8_t* Vs = Vg + (size_t)vrow * 4096 + (size_t)kn * 2 + vcol;
      char* Kd = Klds[cur ^ 1] + dst16;
      char* Vd = Vlds[cur ^ 1] + dst16;
      #pragma unroll
      for (int i = 0; i < 4; ++i) gload_lds16(Ks + (size_t)i * 16 * 1280, Kd + i * 4096);
      #pragma unroll
      for (int i = 0; i < 4; ++i) gload_lds16(Vs + (size_t)i * 32 * 4096, Vd + i * 4096);
    }

    const char* Kc = Klds[cur];
    const char* Vc = Vlds[cur];

    // QK^T for both q-groups; each kf fragment feeds 2 MFMAs
    __builtin_amdgcn_s_setprio(1);
    f32x4 sa0[4] = {}, sa1[4] = {};
    #pragma unroll
    for (int t = 0; t < 4; ++t) {
      #pragma unroll
      for (int c = 0; c < 4; ++c) {
        bf16x8 kf = *(const bf16x8*)(Kc + (t * 16 + lr) * 256 + ((c * 64 + lg * 16) ^ kswz));
        sa0[t] = __builtin_amdgcn_mfma_f32_16x16x32_bf16(kf, qf0[c], sa0[t], 0, 0, 0);
        sa1[t] = __builtin_amdgcn_mfma_f32_16x16x32_bf16(kf, qf1[c], sa1[t], 0, 0, 0);
      }
    }
    __builtin_amdgcn_s_setprio(0);

    // per-group softmax -> P in per-wave LDS -> PV (groups sequential, same wave)
    #pragma unroll
    for (int g = 0; g < 2; ++g) {
      const f32x4* sa = g ? sa1 : sa0;
      f32x4* oa = g ? oa1 : oa0;
      float& m = g ? m1 : m0;
      float& l = g ? l1 : l0;
      const int q0g = q0 + 16 * g;

      float sraw[16];
      if (k0 + 63 > q0g) {
        #pragma unroll
        for (int t = 0; t < 4; ++t)
          #pragma unroll
          for (int r = 0; r < 4; ++r)
            sraw[t * 4 + r] = (k0 + t * 16 + lg * 4 + r <= q0g + lr) ? sa[t][r] : NEGINF;
      } else {
        #pragma unroll
        for (int t = 0; t < 4; ++t)
          #pragma unroll
          for (int r = 0; r < 4; ++r)
            sraw[t * 4 + r] = sa[t][r];
      }
      // raw max tree + 2 shuffles, then one scale
      float a01 = fmaxf(sraw[0], sraw[1]),   a23 = fmaxf(sraw[2], sraw[3]);
      float a45 = fmaxf(sraw[4], sraw[5]),   a67 = fmaxf(sraw[6], sraw[7]);
      float a89 = fmaxf(sraw[8], sraw[9]),   aab = fmaxf(sraw[10], sraw[11]);
      float acd = fmaxf(sraw[12], sraw[13]), aef = fmaxf(sraw[14], sraw[15]);
      float mxr = fmaxf(fmaxf(fmaxf(a01, a23), fmaxf(a45, a67)),
                        fmaxf(fmaxf(a89, aab), fmaxf(acd, aef)));
      mxr = fmaxf(mxr, __shfl_xor(mxr, 16));
      mxr = fmaxf(mxr, __shfl_xor(mxr, 32));
      const float mx_u = mxr * C;
      // defer-max: skip rescale while max growth bounded (values <= 2^8)
      if (!__all(mx_u <= m + 8.0f)) {
        const float mn = fmaxf(m, mx_u);
        const float resc = __builtin_exp2f(m - mn);
        m = mn;
        l *= resc;
        #pragma unroll
        for (int dc = 0; dc < 8; ++dc) {
          oa[dc][0] *= resc; oa[dc][1] *= resc; oa[dc][2] *= resc; oa[dc][3] *= resc;
        }
      }
      const float nm = -m;
      float pv[16];
      #pragma unroll
      for (int i = 0; i < 16; ++i) pv[i] = __builtin_exp2f(fmaf(sraw[i], C, nm));
      float s0 = (pv[0] + pv[1]) + (pv[2] + pv[3]);
      float s1 = (pv[4] + pv[5]) + (pv[6] + pv[7]);
      float s2 = (pv[8] + pv[9]) + (pv[10] + pv[11]);
      float s3 = (pv[12] + pv[13]) + (pv[14] + pv[15]);
      l += (s0 + s1) + (s2 + s3);
      // P -> per-wave LDS: row q=lr, k = 16t + lg*4 + r
      #pragma unroll
      for (int t = 0; t < 4; ++t) {
        union { __bf16 b4[4]; unsigned long long u64; } pk;
        #pragma unroll
        for (int r = 0; r < 4; ++r) pk.b4[r] = (__bf16)pv[t * 4 + r];
        *(unsigned long long*)&pl[lr][t * 16 + lg * 4] = pk.u64;
      }
      bf16x8 pa0 = *(const bf16x8*)&pl[lr][lk];
      bf16x8 pa1 = *(const bf16x8*)&pl[lr][32 + lk];
      __builtin_amdgcn_s_setprio(1);
      #pragma unroll
      for (int dc = 0; dc < 8; ++dc) {
        bf16x8 vf0 = *(const bf16x8*)(Vc + (dc * 16 + lr) * 128 + ((lg * 16) ^ kswz));
        bf16x8 vf1 = *(const bf16x8*)(Vc + (dc * 16 + lr) * 128 + ((64 + lg * 16) ^ kswz));
        oa[dc] = __builtin_amdgcn_mfma_f32_16x16x32_bf16(vf0, pa0, oa[dc], 0, 0, 0);
        oa[dc] = __builtin_amdgcn_mfma_f32_16x16x32_bf16(vf1, pa1, oa[dc], 0, 0, 0);
      }
      __builtin_amdgcn_s_setprio(0);
    }
    cur ^= 1;
  }

  // finalize both groups; accumulate row sum-of-squares of stored bf16 output
  #pragma unroll
  for (int g = 0; g < 2; ++g) {
    f32x4* oa = g ? oa1 : oa0;
    float lf = g ? l1 : l0;
    lf += __shfl_xor(lf, 16);
    lf += __shfl_xor(lf, 32);
    const float inv = 1.0f / lf;
    const size_t obase = ((size_t)(b * 2048 + q0 + 16 * g + lr)) * 2560 + (size_t)h * 128;
    float ssq = 0.f;
    #pragma unroll
    for (int dc = 0; dc < 8; ++dc) {
      union { __bf16 b4[4]; unsigned long long u64; } ok;
      #pragma unroll
      for (int r = 0; r < 4; ++r) {
        ok.b4[r] = (__bf16)(oa[dc][r] * inv);
        const float vq = (float)ok.b4[r];
        ssq += vq * vq;
      }
      *(unsigned long long*)&Ob[obase + dc * 16 + lg * 4] = ok.u64;
    }
    ssq += __shfl_xor(ssq, 16);
    ssq += __shfl_xor(ssq, 32);
    if (lane < 16)
      atomicAdd(&ssb[b * 2048 + q0 + 16 * g + lr], ssq);
  }
}

// ---------- launch ----------
extern "C" void kernel_launch(void* const* d_in, const int* in_sizes, int n_in,
                              void* d_out, int out_size, void* d_ws, size_t ws_size,
                              hipStream_t stream)
{
  const float*    x     = (const float*)d_in[0];
  // d_in[1] = attention_mask (pure causal -> analytic)
  const uint32_t* qw    = (const uint32_t*)d_in[2];  // harness promotes uint8 -> int32
  const uint32_t* kw    = (const uint32_t*)d_in[3];
  const uint32_t* vw    = (const uint32_t*)d_in[4];
  const uint32_t* ow    = (const uint32_t*)d_in[5];
  const float*    qs    = (const float*)d_in[6];
  const float*    ks    = (const float*)d_in[7];
  const float*    vs    = (const float*)d_in[8];
  const float*    os    = (const float*)d_in[9];
  const float*    gnorm = (const float*)d_in[10];

  char* ws = (char*)d_ws;
  uint16_t* xb   = (uint16_t*)(ws + 0);         // 4096x2560 bf16 (x; reused as attn-out)
  uint16_t* wqkv = (uint16_t*)(ws + 20971520);  // 3840x2560 bf16 (dead after GEMM0)
  uint16_t* owb  = (uint16_t*)(ws + 40632320);  // 2560x2560 bf16 (g-folded)
  float*    cosT = (float*)   (ws + 53739520);  // 2048x64 f32
  float*    sinT = (float*)   (ws + 54263808);  // 2048x64 f32
  uint16_t* Qb   = (uint16_t*)(ws + 54788096);  // 4096x2560 bf16 (un-roped Q)
  uint16_t* Kb   = (uint16_t*)(ws + 75759616);  // 4096x640 bf16
  uint16_t* Vt   = (uint16_t*)(ws + 81002496);  // 10x128x2048 bf16
  float*    ssb  = (float*)   (ws + 20971520);  // ss[4096] f32 (reuses dead wqkv; zeroed by k_rope)

  k_prep<<<26752, 256, 0, stream>>>(x, xb, qw, kw, vw, ow, wqkv, owb, gnorm, cosT, sinT);

  k_gemm<0><<<dim3(30, 32), 256, 0, stream>>>(xb, wqkv, Qb, Kb, Vt, nullptr,
                                              qs, ks, vs, 4096, 3840, 2560);
  k_rope<<<5120, 256, 0, stream>>>(Kb, cosT, sinT, 5, 1310720, ssb);

  k_attn<<<dim3(640), 256, 0, stream>>>(Qb, Kb, Vt, xb, cosT, sinT, ssb);

  k_gemm<1><<<dim3(20, 32), 256, 0, stream>>>(xb, owb, nullptr, nullptr, nullptr,
                                              (float*)d_out, os, ssb, nullptr,
                                              4096, 2560, 2560);
}

// Round 20
// 284.920 us; speedup vs baseline: 1.1310x; 1.0101x over previous
//
#include <hip/hip_runtime.h>
#include <cstdint>
#include <cstddef>

// ---------- types ----------
typedef __bf16 bf16x8 __attribute__((ext_vector_type(8)));
typedef float  f32x4  __attribute__((ext_vector_type(4)));
typedef int    i32x4  __attribute__((ext_vector_type(4)));
typedef unsigned short u16x4 __attribute__((ext_vector_type(4)));

#define DEV __device__ __forceinline__
#define NEGINF (-__builtin_inff())

DEV uint16_t f2bf(float f) {
  union { float f; uint32_t u; } v; v.f = f;
  uint32_t u = v.u;
  u += 0x7FFFu + ((u >> 16) & 1u);   // RNE
  return (uint16_t)(u >> 16);
}
DEV float bf2f(uint16_t h) {
  union { uint32_t u; float f; } v; v.u = ((uint32_t)h) << 16;
  return v.f;
}

// async global->LDS, 16B per lane. LDS dest must be wave-uniform base (+lane*16).
DEV void gload_lds16(const void* g, void* l) {
  __builtin_amdgcn_global_load_lds(
      (const __attribute__((address_space(1))) void*)g,
      (__attribute__((address_space(3))) void*)l, 16, 0, 0);
}

// ---------- constants ----------
// B=2 S=2048 HID=2560 NH=20 NKV=5 HD=128 GROUPS=4

// ---------- fused prep: f32->bf16 | ternary unpack (g-folded O) | rope table ----------
__global__ void k_prep(const float* __restrict__ x, uint16_t* __restrict__ xb,
                       const uint32_t* __restrict__ qw, const uint32_t* __restrict__ kw,
                       const uint32_t* __restrict__ vw, const uint32_t* __restrict__ ow,
                       uint16_t* __restrict__ wqkv, uint16_t* __restrict__ owb,
                       const float* __restrict__ g,
                       float* __restrict__ cosT, float* __restrict__ sinT)
{
  const int bid = blockIdx.x, tid = threadIdx.x;
  if (bid < 10240) {
    const int i = bid * 256 + tid;             // < 2621440
    f32x4 v = *(const f32x4*)(x + (size_t)i * 4);
    u16x4 o;
    o[0] = f2bf(v[0]); o[1] = f2bf(v[1]); o[2] = f2bf(v[2]); o[3] = f2bf(v[3]);
    *(u16x4*)(xb + (size_t)i * 4) = o;
  } else if (bid < 26240) {
    const int idx = (bid - 10240) * 256 + tid; // < 4096000
    if (idx < 2457600) {
      int local = (idx < 1638400) ? idx : ((idx < 2048000) ? idx - 1638400 : idx - 2048000);
      const uint32_t* s = (idx < 1638400) ? qw : ((idx < 2048000) ? kw : vw);
      uint32_t b = s[local] & 0xFFu;
      int drow = idx / 640, pc = idx - drow * 640;
      int blk = pc >> 5, j = pc & 31;
      size_t base = (size_t)drow * 2560 + (size_t)blk * 128 + j;
      wqkv[base]      = f2bf((float)((b >> 6) & 3u) - 1.0f);
      wqkv[base + 32] = f2bf((float)((b >> 4) & 3u) - 1.0f);
      wqkv[base + 64] = f2bf((float)((b >> 2) & 3u) - 1.0f);
      wqkv[base + 96] = f2bf((float)(b & 3u) - 1.0f);
    } else {
      int local = idx - 2457600;
      uint32_t b = ow[local] & 0xFFu;
      int drow = local / 640, pc = local - drow * 640;
      int blk = pc >> 5, j = pc & 31;
      int kpos = blk * 128 + j;
      size_t base = (size_t)drow * 2560 + kpos;
      owb[base]      = f2bf(((float)((b >> 6) & 3u) - 1.0f) * g[kpos]);
      owb[base + 32] = f2bf(((float)((b >> 4) & 3u) - 1.0f) * g[kpos + 32]);
      owb[base + 64] = f2bf(((float)((b >> 2) & 3u) - 1.0f) * g[kpos + 64]);
      owb[base + 96] = f2bf(((float)(b & 3u) - 1.0f) * g[kpos + 96]);
    }
  } else {
    const int idx = (bid - 26240) * 256 + tid; // < 131072
    const int s = idx >> 6, i = idx & 63;
    float inv = expf((float)i * (-13.122363377404328f / 64.0f));
    float fr = (float)s * inv;
    cosT[idx] = cosf(fr);
    sinT[idx] = sinf(fr);
  }
}

// ---------- GEMM: C[M,N] = A[M,K] * W[N,K]^T ----------
// global_load_lds(16B) staging, linear LDS + XOR-swizzle (row&7)<<4 on the
// GLOBAL source (rule 21) and on ds_read_b128 fragment reads.
// MODE 0: QKV epilogue; K tiles (n0 in [2560,3200)) apply RoPE in-epilogue via
//   a 32KB LDS stash (tile spans exactly one kvh head; pair col^64 lives in the
//   other wn-wave). MODE 1: f32 out * os * rsqrt(sum5(pss[row])/2560+eps).
template<int MODE>
__global__ __launch_bounds__(256, 2)
void k_gemm(const uint16_t* __restrict__ A, const uint16_t* __restrict__ W,
            uint16_t* __restrict__ Qo, uint16_t* __restrict__ Ko, uint16_t* __restrict__ Vo,
            float* __restrict__ Fo,
            const float* __restrict__ s0p, const float* __restrict__ s1p, const float* __restrict__ s2p,
            const float* __restrict__ cosT, const float* __restrict__ sinT,
            int M, int N, int K)
{
  __shared__ uint16_t smem[2][128 * 64];   // As = smem[0], Bs = smem[1]; 32 KB total
  const int tid = threadIdx.x;
  const int n0 = blockIdx.x * 128, m0 = blockIdx.y * 128;
  const int lane = tid & 63, w = tid >> 6;
  const int wm = (w >> 1) * 64, wn = (w & 1) * 64;
  const int lr = lane & 15, lg = lane >> 4, lk = lg * 8;
  const size_t K2 = (size_t)K * 2;
  f32x4 acc[4][4] = {};

  const int srow = tid >> 3;                       // 0..31 (+i*32)
  const int cprime = ((tid & 7) * 16) ^ ((srow & 7) << 4);
  const uint8_t* Ag = (const uint8_t*)A + (size_t)(m0 + srow) * K2 + cprime;
  const uint8_t* Wg = (const uint8_t*)W + (size_t)(n0 + srow) * K2 + cprime;
  char* Al = (char*)smem[0] + w * 1024;            // wave-uniform dest (+i*4096)
  char* Bl = (char*)smem[1] + w * 1024;

  for (size_t k0b = 0; k0b < K2; k0b += 128) {
    #pragma unroll
    for (int i = 0; i < 4; ++i)
      gload_lds16(Ag + (size_t)(i * 32) * K2 + k0b, Al + i * 4096);
    #pragma unroll
    for (int i = 0; i < 4; ++i)
      gload_lds16(Wg + (size_t)(i * 32) * K2 + k0b, Bl + i * 4096);
    __syncthreads();
    #pragma unroll
    for (int kc = 0; kc < 64; kc += 32) {
      bf16x8 a[4], b[4];
      #pragma unroll
      for (int i = 0; i < 4; ++i) {
        const int r = wm + i * 16 + lr;
        a[i] = *(const bf16x8*)((const char*)smem[0] + r * 128 + (((kc + lk) * 2) ^ ((r & 7) << 4)));
      }
      #pragma unroll
      for (int j = 0; j < 4; ++j) {
        const int r = wn + j * 16 + lr;
        b[j] = *(const bf16x8*)((const char*)smem[1] + r * 128 + (((kc + lk) * 2) ^ ((r & 7) << 4)));
      }
      #pragma unroll
      for (int i = 0; i < 4; ++i)
        #pragma unroll
        for (int j = 0; j < 4; ++j)
          acc[i][j] = __builtin_amdgcn_mfma_f32_16x16x32_bf16(a[i], b[j], acc[i][j], 0, 0, 0);
    }
    __syncthreads();
  }

  if (MODE == 0) {
    if (n0 >= 2560 && n0 < 3200) {
      // ---- K tile: fused RoPE via LDS exchange ----
      const float ks = *s1p;
      uint16_t* Kx = (uint16_t*)smem;   // [128][128] bf16 = 32KB (k-loop done; LDS free)
      #pragma unroll
      for (int i = 0; i < 4; ++i) {
        const int rowl = wm + i * 16 + lg * 4;
        #pragma unroll
        for (int j = 0; j < 4; ++j) {
          const int coll = wn + j * 16 + lr;
          #pragma unroll
          for (int r = 0; r < 4; ++r)
            Kx[(rowl + r) * 128 + coll] = f2bf(acc[i][j][r] * ks);
        }
      }
      __syncthreads();
      const int ncol = n0 - 2560;
      #pragma unroll
      for (int i = 0; i < 4; ++i) {
        const int rowl = wm + i * 16 + lg * 4;
        #pragma unroll
        for (int j = 0; j < 4; ++j) {
          const int coll = wn + j * 16 + lr;
          const int d = coll & 63;
          #pragma unroll
          for (int r = 0; r < 4; ++r) {
            const int rr = m0 + rowl + r;
            const int spos = rr & 2047;
            const float xv = bf2f(Kx[(rowl + r) * 128 + coll]);
            const float pv = bf2f(Kx[(rowl + r) * 128 + (coll ^ 64)]);
            const float cs = cosT[spos * 64 + d];
            const float sn = sinT[spos * 64 + d];
            const float out = (coll < 64) ? (xv * cs - pv * sn) : (xv * cs + pv * sn);
            Ko[(size_t)rr * 640 + ncol + coll] = f2bf(out);
          }
        }
      }
    } else {
      const float qs = *s0p, vs = *s2p;
      #pragma unroll
      for (int i = 0; i < 4; ++i) {
        const int rowb = m0 + wm + i * 16 + lg * 4;
        #pragma unroll
        for (int j = 0; j < 4; ++j) {
          const int col = n0 + wn + j * 16 + lr;
          #pragma unroll
          for (int r = 0; r < 4; ++r) {
            const int rr = rowb + r;
            const float v = acc[i][j][r];
            if (col < 2560) {
              Qo[(size_t)rr * 2560 + col] = f2bf(v * qs);
            } else {
              const int n2 = col - 3200;
              const int kvh = n2 >> 7, d = n2 & 127;
              const int bb = rr >> 11, ss2 = rr & 2047;
              Vo[(((size_t)(bb * 5 + kvh) * 128 + d) << 11) + ss2] = f2bf(v * vs);
            }
          }
        }
      }
    }
  } else {
    const float os = *s0p;          // s1p = pss[5][4096] per-kvh partial sumsq
    #pragma unroll
    for (int i = 0; i < 4; ++i) {
      const int rowb = m0 + wm + i * 16 + lg * 4;
      float rs4[4];
      #pragma unroll
      for (int r = 0; r < 4; ++r) {
        const int row = rowb + r;
        const float tot = s1p[row] + s1p[4096 + row] + s1p[8192 + row] +
                          s1p[12288 + row] + s1p[16384 + row];
        rs4[r] = rsqrtf(tot * (1.0f / 2560.0f) + 1e-6f) * os;
      }
      #pragma unroll
      for (int j = 0; j < 4; ++j) {
        const int col = n0 + wn + j * 16 + lr;
        #pragma unroll
        for (int r = 0; r < 4; ++r)
          Fo[(size_t)(rowb + r) * N + col] = acc[i][j][r] * rs4[r];
      }
    }
  }
}

// ---------- flash attention (GQA-shared K+V LDS, 32 q-rows/wave, fused Q-rope) ----------
// KVBLK=64 anchor (121us). Epilogue: per-block partial sum-of-squares of the stored
// bf16 output, reduced across the 4 waves via LDS, plain-stored to pss[kvh][row]
// (each (b,st) row-range has exactly 5 kvh blocks -> every slot written once; no
// zero-init, no atomics). GEMM<1> sums the 5 partials and applies rsqrt.
__global__ __launch_bounds__(256, 2)
void k_attn(const uint16_t* __restrict__ Q, const uint16_t* __restrict__ Kb,
            const uint16_t* __restrict__ Vt, uint16_t* __restrict__ Ob,
            const float* __restrict__ cosT, const float* __restrict__ sinT,
            float* __restrict__ pss)
{
  __shared__ char Klds[2][16384];         // [64 k][128 d] bf16, swizzled
  __shared__ char Vlds[2][16384];         // [128 d][64 k] bf16, swizzled
  __shared__ uint16_t p_lds[4][16][72];   // per-wave P tile (groups sequential)
  __shared__ float xss[4][32];            // per-wave row sumsq partials

  // XCD-chunked remap (blockIdx%8 = XCD): 80 consecutive strips per XCD.
  const int lin = blockIdx.x;                            // 0..639
  const int gslot = (lin & 7) * 80 + (lin >> 3);
  const int bk = gslot >> 6;                             // 0..9
  const int st = 63 - (gslot & 63);                      // strip32 id, heavy-first
  const int b = bk / 5, kvh = bk - b * 5;

  const int tid = threadIdx.x, lane = tid & 63, w = tid >> 6;
  const int lr = lane & 15, lg = lane >> 4, lk = lg * 8;
  const int h = kvh * 4 + w;                             // this wave's q-head
  uint16_t (*pl)[72] = p_lds[w];
  const int kswz = (lr & 7) << 4;

  const uint8_t* Kg = (const uint8_t*)(Kb + (size_t)b * 2048 * 640 + (size_t)kvh * 128);
  const uint8_t* Vg = (const uint8_t*)(Vt + ((size_t)(b * 5 + kvh) * 128) * 2048);

  // staging coords (256 threads cover each 16KB tile in 4 x 16B rounds)
  const int krow = tid >> 4;                             // K: row 0..15 (+16i)
  const int kcol = ((tid & 15) * 16) ^ ((krow & 7) << 4);
  const int vrow = tid >> 3;                             // V: row 0..31 (+32i)
  const int vcol = ((tid & 7) * 16) ^ ((vrow & 7) << 4);
  const int dst16 = tid * 16;

  const float C = 0.127531019577f;        // (1/sqrt(128)) * log2(e)

  const int q0 = st * 32;                 // rows q0..q0+31; group g rows q0+16g+lr
  const int ns = (q0 + 95) >> 6;          // 64-wide k-steps

  bf16x8 qf0[4], qf1[4];
  {
    const size_t qb0 = ((size_t)(b * 2048 + q0 + lr)) * 2560 + (size_t)h * 128 + lk;
    #pragma unroll
    for (int c = 0; c < 4; ++c) {
      qf0[c] = *(const bf16x8*)&Q[qb0 + c * 32];
      qf1[c] = *(const bf16x8*)&Q[qb0 + 16 * 2560 + c * 32];
    }
  }
  // in-register RoPE on Q (pairs: qf[c][j] <-> qf[c+2][j], d = 32c+8lg+j)
  #pragma unroll
  for (int g = 0; g < 2; ++g) {
    bf16x8* qf = g ? qf1 : qf0;
    const int s = q0 + 16 * g + lr;
    const int tb0 = s * 64 + lg * 8;
    #pragma unroll
    for (int c = 0; c < 2; ++c) {
      const int tb = tb0 + c * 32;
      f32x4 csa = *(const f32x4*)&cosT[tb];
      f32x4 csb = *(const f32x4*)&cosT[tb + 4];
      f32x4 sna = *(const f32x4*)&sinT[tb];
      f32x4 snb = *(const f32x4*)&sinT[tb + 4];
      #pragma unroll
      for (int j = 0; j < 8; ++j) {
        const float cs = (j < 4) ? csa[j] : csb[j - 4];
        const float sn = (j < 4) ? sna[j] : snb[j - 4];
        const float x1 = (float)qf[c][j], x2 = (float)qf[c + 2][j];
        qf[c][j]     = (__bf16)(x1 * cs - x2 * sn);
        qf[c + 2][j] = (__bf16)(x2 * cs + x1 * sn);
      }
    }
  }

  // prologue: stage step-0 K/V into buf 0
  {
    const uint8_t* Ks = Kg + (size_t)krow * 1280 + kcol;
    const uint8_t* Vs = Vg + (size_t)vrow * 4096 + vcol;
    #pragma unroll
    for (int i = 0; i < 4; ++i) gload_lds16(Ks + (size_t)i * 16 * 1280, Klds[0] + dst16 + i * 4096);
    #pragma unroll
    for (int i = 0; i < 4; ++i) gload_lds16(Vs + (size_t)i * 32 * 4096, Vlds[0] + dst16 + i * 4096);
  }

  int cur = 0;
  float m0 = NEGINF, m1 = NEGINF, l0 = 0.f, l1 = 0.f;
  f32x4 oa0[8] = {}, oa1[8] = {};

  #pragma unroll 1
  for (int stp = 0; stp < ns; ++stp) {
    const int k0 = stp * 64;
    __syncthreads();   // implicit vmcnt(0): tile[cur] landed (flew over previous step)

    if (stp + 1 < ns) {
      const int kn = k0 + 64;
      const uint8_t* Ks = Kg + (size_t)(kn + krow) * 1280 + kcol;
      const uint8_t* Vs = Vg + (size_t)vrow * 4096 + (size_t)kn * 2 + vcol;
      char* Kd = Klds[cur ^ 1] + dst16;
      char* Vd = Vlds[cur ^ 1] + dst16;
      #pragma unroll
      for (int i = 0; i < 4; ++i) gload_lds16(Ks + (size_t)i * 16 * 1280, Kd + i * 4096);
      #pragma unroll
      for (int i = 0; i < 4; ++i) gload_lds16(Vs + (size_t)i * 32 * 4096, Vd + i * 4096);
    }

    const char* Kc = Klds[cur];
    const char* Vc = Vlds[cur];

    // QK^T for both q-groups; each kf fragment feeds 2 MFMAs
    __builtin_amdgcn_s_setprio(1);
    f32x4 sa0[4] = {}, sa1[4] = {};
    #pragma unroll
    for (int t = 0; t < 4; ++t) {
      #pragma unroll
      for (int c = 0; c < 4; ++c) {
        bf16x8 kf = *(const bf16x8*)(Kc + (t * 16 + lr) * 256 + ((c * 64 + lg * 16) ^ kswz));
        sa0[t] = __builtin_amdgcn_mfma_f32_16x16x32_bf16(kf, qf0[c], sa0[t], 0, 0, 0);
        sa1[t] = __builtin_amdgcn_mfma_f32_16x16x32_bf16(kf, qf1[c], sa1[t], 0, 0, 0);
      }
    }
    __builtin_amdgcn_s_setprio(0);

    // per-group softmax -> P in per-wave LDS -> PV (groups sequential, same wave)
    #pragma unroll
    for (int g = 0; g < 2; ++g) {
      const f32x4* sa = g ? sa1 : sa0;
      f32x4* oa = g ? oa1 : oa0;
      float& m = g ? m1 : m0;
      float& l = g ? l1 : l0;
      const int q0g = q0 + 16 * g;

      float sraw[16];
      if (k0 + 63 > q0g) {
        #pragma unroll
        for (int t = 0; t < 4; ++t)
          #pragma unroll
          for (int r = 0; r < 4; ++r)
            sraw[t * 4 + r] = (k0 + t * 16 + lg * 4 + r <= q0g + lr) ? sa[t][r] : NEGINF;
      } else {
        #pragma unroll
        for (int t = 0; t < 4; ++t)
          #pragma unroll
          for (int r = 0; r < 4; ++r)
            sraw[t * 4 + r] = sa[t][r];
      }
      // raw max tree + 2 shuffles, then one scale
      float a01 = fmaxf(sraw[0], sraw[1]),   a23 = fmaxf(sraw[2], sraw[3]);
      float a45 = fmaxf(sraw[4], sraw[5]),   a67 = fmaxf(sraw[6], sraw[7]);
      float a89 = fmaxf(sraw[8], sraw[9]),   aab = fmaxf(sraw[10], sraw[11]);
      float acd = fmaxf(sraw[12], sraw[13]), aef = fmaxf(sraw[14], sraw[15]);
      float mxr = fmaxf(fmaxf(fmaxf(a01, a23), fmaxf(a45, a67)),
                        fmaxf(fmaxf(a89, aab), fmaxf(acd, aef)));
      mxr = fmaxf(mxr, __shfl_xor(mxr, 16));
      mxr = fmaxf(mxr, __shfl_xor(mxr, 32));
      const float mx_u = mxr * C;
      // defer-max: skip rescale while max growth bounded (values <= 2^8)
      if (!__all(mx_u <= m + 8.0f)) {
        const float mn = fmaxf(m, mx_u);
        const float resc = __builtin_exp2f(m - mn);
        m = mn;
        l *= resc;
        #pragma unroll
        for (int dc = 0; dc < 8; ++dc) {
          oa[dc][0] *= resc; oa[dc][1] *= resc; oa[dc][2] *= resc; oa[dc][3] *= resc;
        }
      }
      const float nm = -m;
      float pv[16];
      #pragma unroll
      for (int i = 0; i < 16; ++i) pv[i] = __builtin_exp2f(fmaf(sraw[i], C, nm));
      float s0 = (pv[0] + pv[1]) + (pv[2] + pv[3]);
      float s1 = (pv[4] + pv[5]) + (pv[6] + pv[7]);
      float s2 = (pv[8] + pv[9]) + (pv[10] + pv[11]);
      float s3 = (pv[12] + pv[13]) + (pv[14] + pv[15]);
      l += (s0 + s1) + (s2 + s3);
      // P -> per-wave LDS: row q=lr, k = 16t + lg*4 + r
      #pragma unroll
      for (int t = 0; t < 4; ++t) {
        union { __bf16 b4[4]; unsigned long long u64; } pk;
        #pragma unroll
        for (int r = 0; r < 4; ++r) pk.b4[r] = (__bf16)pv[t * 4 + r];
        *(unsigned long long*)&pl[lr][t * 16 + lg * 4] = pk.u64;
      }
      bf16x8 pa0 = *(const bf16x8*)&pl[lr][lk];
      bf16x8 pa1 = *(const bf16x8*)&pl[lr][32 + lk];
      __builtin_amdgcn_s_setprio(1);
      #pragma unroll
      for (int dc = 0; dc < 8; ++dc) {
        bf16x8 vf0 = *(const bf16x8*)(Vc + (dc * 16 + lr) * 128 + ((lg * 16) ^ kswz));
        bf16x8 vf1 = *(const bf16x8*)(Vc + (dc * 16 + lr) * 128 + ((64 + lg * 16) ^ kswz));
        oa[dc] = __builtin_amdgcn_mfma_f32_16x16x32_bf16(vf0, pa0, oa[dc], 0, 0, 0);
        oa[dc] = __builtin_amdgcn_mfma_f32_16x16x32_bf16(vf1, pa1, oa[dc], 0, 0, 0);
      }
      __builtin_amdgcn_s_setprio(0);
    }
    cur ^= 1;
  }

  // finalize both groups; per-wave row sumsq of stored bf16 output
  float ssqg[2];
  #pragma unroll
  for (int g = 0; g < 2; ++g) {
    f32x4* oa = g ? oa1 : oa0;
    float lf = g ? l1 : l0;
    lf += __shfl_xor(lf, 16);
    lf += __shfl_xor(lf, 32);
    const float inv = 1.0f / lf;
    const size_t obase = ((size_t)(b * 2048 + q0 + 16 * g + lr)) * 2560 + (size_t)h * 128;
    float ssq = 0.f;
    #pragma unroll
    for (int dc = 0; dc < 8; ++dc) {
      union { __bf16 b4[4]; unsigned long long u64; } ok;
      #pragma unroll
      for (int r = 0; r < 4; ++r) {
        ok.b4[r] = (__bf16)(oa[dc][r] * inv);
        const float vq = (float)ok.b4[r];
        ssq += vq * vq;
      }
      *(unsigned long long*)&Ob[obase + dc * 16 + lg * 4] = ok.u64;
    }
    ssq += __shfl_xor(ssq, 16);
    ssq += __shfl_xor(ssq, 32);
    ssqg[g] = ssq;
  }
  // cross-wave reduce (4 heads of this kvh) -> plain store of the block's partial
  if (lane < 16) { xss[w][lr] = ssqg[0]; xss[w][16 + lr] = ssqg[1]; }
  __syncthreads();
  if (tid < 32) {
    const float tot = xss[0][tid] + xss[1][tid] + xss[2][tid] + xss[3][tid];
    pss[kvh * 4096 + b * 2048 + q0 + tid] = tot;
  }
}

// ---------- launch ----------
extern "C" void kernel_launch(void* const* d_in, const int* in_sizes, int n_in,
                              void* d_out, int out_size, void* d_ws, size_t ws_size,
                              hipStream_t stream)
{
  const float*    x     = (const float*)d_in[0];
  // d_in[1] = attention_mask (pure causal -> analytic)
  const uint32_t* qw    = (const uint32_t*)d_in[2];  // harness promotes uint8 -> int32
  const uint32_t* kw    = (const uint32_t*)d_in[3];
  const uint32_t* vw    = (const uint32_t*)d_in[4];
  const uint32_t* ow    = (const uint32_t*)d_in[5];
  const float*    qs    = (const float*)d_in[6];
  const float*    ks    = (const float*)d_in[7];
  const float*    vs    = (const float*)d_in[8];
  const float*    os    = (const float*)d_in[9];
  const float*    gnorm = (const float*)d_in[10];

  char* ws = (char*)d_ws;
  uint16_t* xb   = (uint16_t*)(ws + 0);         // 4096x2560 bf16 (x; reused as attn-out)
  uint16_t* wqkv = (uint16_t*)(ws + 20971520);  // 3840x2560 bf16 (dead after GEMM0)
  uint16_t* owb  = (uint16_t*)(ws + 40632320);  // 2560x2560 bf16 (g-folded)
  float*    cosT = (float*)   (ws + 53739520);  // 2048x64 f32
  float*    sinT = (float*)   (ws + 54263808);  // 2048x64 f32
  uint16_t* Qb   = (uint16_t*)(ws + 54788096);  // 4096x2560 bf16 (un-roped Q)
  uint16_t* Kb   = (uint16_t*)(ws + 75759616);  // 4096x640 bf16 (roped in GEMM0)
  uint16_t* Vt   = (uint16_t*)(ws + 81002496);  // 10x128x2048 bf16
  float*    pss  = (float*)   (ws + 20971520);  // pss[5][4096] f32, aliases wqkv:
  // wqkv is read ONLY by GEMM0; pss is written by k_attn (after GEMM0, stream-
  // ordered) and read by GEMM1 -> no overlap of live ranges, no init needed
  // (every slot plain-stored exactly once by its (b,kvh,st) block).

  k_prep<<<26752, 256, 0, stream>>>(x, xb, qw, kw, vw, ow, wqkv, owb, gnorm, cosT, sinT);

  k_gemm<0><<<dim3(30, 32), 256, 0, stream>>>(xb, wqkv, Qb, Kb, Vt, nullptr,
                                              qs, ks, vs, cosT, sinT, 4096, 3840, 2560);

  k_attn<<<dim3(640), 256, 0, stream>>>(Qb, Kb, Vt, xb, cosT, sinT, pss);

  k_gemm<1><<<dim3(20, 32), 256, 0, stream>>>(xb, owb, nullptr, nullptr, nullptr,
                                              (float*)d_out, os, pss, nullptr, cosT, sinT,
                                              4096, 2560, 2560);
}